// Round 5
// baseline (520.932 us; speedup 1.0000x reference)
//
#include <hip/hip_runtime.h>

// CRF sequence labeling: B=64, S=512, H=1024, L=9
// Pipeline (2 kernels):
//   K1 logits_chunk_kernel (512 thr, 64 rows = 2 chunks per block, grid 512):
//        phase A (GEMM): feats[row][l] = (inp[row,:]·W[l,:] + b[l]) * log2e
//          R5 streaming layout: 16-lane group owns one row; lane p covers the
//          16 float4 granules {c*256+qq*64+p*4}. All 16 global loads issue
//          back-to-back from ONE base reg with constant offsets (max MLP);
//          all 144 W ds_reads are base+immediate-offset, broadcast across
//          q-groups (conflict-free). 4-level shuffle reduce per row.
//        phase B (waves 0-3): per chunk, 9 row-recursions of the 9x9
//          log2-semiring chunk transfer matrix P_c (row i = e_i ⊗ M_ts ⊗ ...;
//          masked steps contribute identity). 9-lane groups, shuffle recursion.
//        Also zeroes out[0] for K3's atomic accumulation.
//   K3 final_kernel : per batch: gold path score + alpha0 ⊗ P_0 ⊗ ... ⊗ P_15;
//        atomicAdd((norm-score)*ln2/B) into out[0].
// All LSE math in base-2 domain (inputs pre-scaled by log2 e) so
// LSE = max + log2(sum 2^x) maps to raw v_exp_f32/v_log_f32.

#define BATCH 64
#define SEQ   512
#define HID   1024
#define NLAB  9
#define CHUNK 32
#define NCHUNK (SEQ / CHUNK)   // 16
#define RPB   64               // rows per block (= 2 chunks)

__device__ __forceinline__ float exp2_fast(float x) { return __builtin_amdgcn_exp2f(x); }
__device__ __forceinline__ float log2_fast(float x) { return __builtin_amdgcn_logf(x); }

#define LOG2E 1.4426950408889634f
#define LN2   0.6931471805599453f

// ---------------------------------------------------------------------------
// K1. Grid: 512 blocks x 512 threads (8 waves). Block = rows [bid*64, bid*64+64)
// = batch b = bid>>3, chunks c = (bid&7)*2 + {0,1}.
// GEMM: wave wv, pass pp in {0,1}: q-group (lane>>4) computes row
// wv*8 + pp*4 + q; lane p = lane&15 covers granules g=(c<<2|qq):
// byte offset c*1024 + qq*256 + p*16 within the row (and same within W row l).
// ---------------------------------------------------------------------------
__global__ __launch_bounds__(512, 4) void logits_chunk_kernel(
    const float* __restrict__ inp, const float* __restrict__ Wg,
    const float* __restrict__ bias, const float* __restrict__ trans,
    const int* __restrict__ mask, float* __restrict__ feats,
    float* __restrict__ P, float* __restrict__ out)
{
    if (blockIdx.x == 0 && threadIdx.x == 0) out[0] = 0.0f;  // for K3's atomics

    __shared__ float Wl[NLAB * HID];       // 36 KB
    __shared__ float femit[RPB][NLAB];     // 2.25 KB: this block's emissions
    const int tid = threadIdx.x;
    for (int s = tid; s < NLAB * HID; s += 512)
        Wl[s] = Wg[s];
    __syncthreads();

    const int lane = tid & 63;
    const int wv   = tid >> 6;       // 0..7
    const int p    = lane & 15;      // granule position within row
    const int q    = lane >> 4;      // row within pass

    float bl[NLAB];
    #pragma unroll
    for (int l = 0; l < NLAB; ++l) bl[l] = bias[l];

    #pragma unroll 1
    for (int pp = 0; pp < 2; ++pp) {
        const int  lrow = wv * 8 + pp * 4 + q;               // 0..63
        const long grow = (long)blockIdx.x * RPB + lrow;
        const float* rb = inp + grow * HID + p * 4;          // lane base
        // 16 independent coalesced loads, all constant offsets from rb
        float4 xs[16];
        #pragma unroll
        for (int g = 0; g < 16; ++g)
            xs[g] = *(const float4*)(rb + (g >> 2) * 256 + (g & 3) * 64);

        const float* wb = Wl + p * 4;                        // lane LDS base
        float acc[NLAB];
        #pragma unroll
        for (int l = 0; l < NLAB; ++l) {
            float a = 0.0f;
            #pragma unroll
            for (int g = 0; g < 16; ++g) {
                float4 w4 = *(const float4*)(wb + l * HID + (g >> 2) * 256 + (g & 3) * 64);
                a = fmaf(xs[g].x, w4.x, a);
                a = fmaf(xs[g].y, w4.y, a);
                a = fmaf(xs[g].z, w4.z, a);
                a = fmaf(xs[g].w, w4.w, a);
            }
            acc[l] = a;
        }

        // reduce across the 16-lane group (xor masks 1,2,4,8 stay in group)
        #pragma unroll
        for (int l = 0; l < NLAB; ++l) {
            float a = acc[l];
            a += __shfl_xor(a, 8, 64);
            a += __shfl_xor(a, 4, 64);
            a += __shfl_xor(a, 2, 64);
            a += __shfl_xor(a, 1, 64);
            acc[l] = a;
        }
        if (p == 0) {
            float* o = feats + grow * NLAB;
            #pragma unroll
            for (int l = 0; l < NLAB; ++l) {
                float f = (acc[l] + bl[l]) * LOG2E;
                o[l] = f;  femit[lrow][l] = f;
            }
        }
    }
    __syncthreads();

    // ---- phase B: chunk recursions (waves 0-3; block holds 2 chunks) ----
    if (wv >= 4) return;

    const int half = wv >> 1;        // which of the block's 2 chunks
    const int sub  = wv & 1;         // 0: rows 0..6, 1: rows 7..8
    const int b = blockIdx.x >> 3;
    const int c = ((blockIdx.x & 7) << 1) | half;   // global chunk index
    const int crow0 = half * CHUNK;                 // femit row base

    int g = lane / 9;
    const int jj = lane - g * 9;     // 0..8 always
    bool act = sub ? (g < 2) : (g < 7);
    int i = act ? (sub * 7 + g) : 0; // P-row 0..8
    const int sbase = g * 9;

    float tr[NLAB];
    #pragma unroll
    for (int k = 0; k < NLAB; ++k) tr[k] = trans[k * NLAB + jj] * LOG2E;
    const float tri = trans[i * NLAB + jj] * LOG2E;

    const int* mb = mask + b * SEQ + c * CHUNK;   // chunk-local mask base
    const int ts = (c == 0) ? 1 : 0;              // chunk-local start step

    float a;
    {
        int m0 = mb[ts];
        float e0 = femit[crow0 + ts][jj];
        float aid = (i == jj) ? 0.0f : -1e30f;
        a = (m0 > 0) ? (tri + e0) : aid;
    }

    int m_nxt = mb[ts + 1];
    for (int t = ts + 1; t < CHUNK; ++t) {
        float e = femit[crow0 + t][jj];
        int  mt = m_nxt;
        if (t + 1 < CHUNK) m_nxt = mb[t + 1];     // prefetch next step's mask
        float v[NLAB];
        #pragma unroll
        for (int k = 0; k < NLAB; ++k) v[k] = __shfl(a, sbase + k, 64) + tr[k];
        float m01 = fmaxf(v[0], v[1]), m23 = fmaxf(v[2], v[3]);
        float m45 = fmaxf(v[4], v[5]), m67 = fmaxf(v[6], v[7]);
        float mx = fmaxf(fmaxf(fmaxf(m01, m23), fmaxf(m45, m67)), v[8]);
        float s = 0.0f;
        #pragma unroll
        for (int k = 0; k < NLAB; ++k) s += exp2_fast(v[k] - mx);
        float an = mx + log2_fast(s) + e;
        a = (mt > 0) ? an : a;
    }
    if (act)
        P[(long)(b * NCHUNK + c) * 81 + i * NLAB + jj] = a;
}

// ---------------------------------------------------------------------------
// K3: per-batch finalize. Grid: 64 blocks x 64.
//  - gold path score (all 64 lanes, strided over t, then wave-reduce)
//  - alpha = alpha0 ⊗ P_0 ⊗ ... ⊗ P_15 (lanes replicate j = lane%9)
//  - atomicAdd (norm - score) * ln2/B into out[0] (zeroed by K1)
// ---------------------------------------------------------------------------
__global__ __launch_bounds__(64) void final_kernel(
    const float* __restrict__ feats, const float* __restrict__ trans,
    const float* __restrict__ startv, const float* __restrict__ endv,
    const int* __restrict__ labels, const int* __restrict__ mask,
    const float* __restrict__ P, float* __restrict__ out)
{
    const int b = blockIdx.x, lane = threadIdx.x;
    const float* fb = feats + (long)b * SEQ * NLAB;
    const int* lb = labels + b * SEQ;
    const int* mb = mask + b * SEQ;

    // ---- gold score ----
    float gsum = 0.0f; int msum = 0;
    for (int t = lane; t < SEQ; t += 64) {
        int tag = lb[t];
        int mt = mb[t];
        if (mt > 0) {
            gsum += fb[t * NLAB + tag];            // feats already *K
            msum++;
            if (t > 0) gsum += trans[lb[t - 1] * NLAB + tag] * LOG2E;
        }
    }
    #pragma unroll
    for (int off = 32; off > 0; off >>= 1) {
        gsum += __shfl_xor(gsum, off, 64);
        msum += __shfl_xor(msum, off, 64);
    }

    // ---- alpha chain over chunk matrices ----
    const int j = lane % 9;      // lanes >=9 replicate; shuffles read lanes 0..8
    float al = fb[j] + startv[j] * LOG2E;
    const float* Pb = P + (long)b * NCHUNK * 81;
    float pc[NLAB];
    #pragma unroll
    for (int i = 0; i < NLAB; ++i) pc[i] = Pb[i * NLAB + j];
    #pragma unroll
    for (int c = 0; c < NCHUNK; ++c) {
        float pn[NLAB];
        if (c < NCHUNK - 1) {
            #pragma unroll
            for (int i = 0; i < NLAB; ++i) pn[i] = Pb[(c + 1) * 81 + i * NLAB + j];
        } else {
            #pragma unroll
            for (int i = 0; i < NLAB; ++i) pn[i] = 0.0f;
        }
        float v[NLAB];
        #pragma unroll
        for (int i = 0; i < NLAB; ++i) v[i] = __shfl(al, i, 64) + pc[i];
        float m01 = fmaxf(v[0], v[1]), m23 = fmaxf(v[2], v[3]);
        float m45 = fmaxf(v[4], v[5]), m67 = fmaxf(v[6], v[7]);
        float mx = fmaxf(fmaxf(fmaxf(m01, m23), fmaxf(m45, m67)), v[8]);
        float s = 0.0f;
        #pragma unroll
        for (int i = 0; i < NLAB; ++i) s += exp2_fast(v[i] - mx);
        al = mx + log2_fast(s);
        #pragma unroll
        for (int i = 0; i < NLAB; ++i) pc[i] = pn[i];
    }
    al += endv[j] * LOG2E;

    // LSE over j (lanes 0..8 hold the distinct values)
    float v[NLAB];
    #pragma unroll
    for (int i = 0; i < NLAB; ++i) v[i] = __shfl(al, i, 64);
    float m01 = fmaxf(v[0], v[1]), m23 = fmaxf(v[2], v[3]);
    float m45 = fmaxf(v[4], v[5]), m67 = fmaxf(v[6], v[7]);
    float mx = fmaxf(fmaxf(fmaxf(m01, m23), fmaxf(m45, m67)), v[8]);
    float s = 0.0f;
    #pragma unroll
    for (int i = 0; i < NLAB; ++i) s += exp2_fast(v[i] - mx);
    float norm = mx + log2_fast(s);

    if (lane == 0) {
        int li = (msum > 0) ? (msum - 1) : 0;
        float score = gsum + startv[lb[0]] * LOG2E + endv[lb[li]] * LOG2E;
        atomicAdd(out, (norm - score) * (LN2 / (float)BATCH));
    }
}

extern "C" void kernel_launch(void* const* d_in, const int* in_sizes, int n_in,
                              void* d_out, int out_size, void* d_ws, size_t ws_size,
                              hipStream_t stream)
{
    const float* inp    = (const float*)d_in[0];
    const int*   labels = (const int*)d_in[1];
    const int*   mask   = (const int*)d_in[2];
    const float* W      = (const float*)d_in[3];
    const float* bias   = (const float*)d_in[4];
    const float* trans  = (const float*)d_in[5];
    const float* startv = (const float*)d_in[6];
    const float* endv   = (const float*)d_in[7];

    float* feats = (float*)d_ws;                    // B*S*L = 294912 floats
    float* P     = feats + BATCH * SEQ * NLAB;      // B*NCHUNK*81 = 82944 floats
    float* out   = (float*)d_out;

    hipLaunchKernelGGL(logits_chunk_kernel, dim3(BATCH * SEQ / RPB), dim3(512), 0,
                       stream, inp, W, bias, trans, mask, feats, P, out);
    hipLaunchKernelGGL(final_kernel, dim3(BATCH), dim3(64), 0, stream,
                       feats, trans, startv, endv, labels, mask, P, out);
}

// Round 17
// 246.767 us; speedup vs baseline: 2.1110x; 2.1110x over previous
//
#include <hip/hip_runtime.h>

// CRF sequence labeling: B=64, S=512, H=1024, L=9
// Pipeline (2 kernels):
//   K1 logits_chunk_kernel (256 thr, 64 rows = 2 chunks per block, grid 512):
//        phase A (GEMM): feats[row][l] = (inp[row,:]·W[l,:] + b[l]) * log2e
//          R6: 4 rows per lane (16-lane group owns rows grp*4..+3). Per
//          128-col slice: 8 independent coalesced float4 global loads from
//          one base; each W float4 (LDS, immediate-offset, broadcast) feeds
//          16 FMAs (4 rows x 4 elems). 256-thr blocks + 36KB LDS pin the
//          occupancy target at 16 waves/CU -> VGPR cap 128, no spill
//          (R5's 512-thr blocks triggered a 64-VGPR target and total spill:
//          WRITE_SIZE 447MB of scratch. Never again.)
//        phase B (waves 0-3): per chunk, 9 row-recursions of the 9x9
//          log2-semiring chunk transfer matrix P_c; 9-lane groups, shuffle
//          recursion; masked steps contribute identity.
//        Also zeroes out[0] for K3's atomic accumulation.
//   K3 final_kernel : per batch: gold path score + alpha0 ⊗ P_0 ⊗ ... ⊗ P_15;
//        atomicAdd((norm-score)*ln2/B) into out[0].
// All LSE math in base-2 domain (inputs pre-scaled by log2 e) so
// LSE = max + log2(sum 2^x) maps to raw v_exp_f32/v_log_f32.

#define BATCH 64
#define SEQ   512
#define HID   1024
#define NLAB  9
#define CHUNK 32
#define NCHUNK (SEQ / CHUNK)   // 16
#define RPB   64               // rows per block (= 2 chunks)

__device__ __forceinline__ float exp2_fast(float x) { return __builtin_amdgcn_exp2f(x); }
__device__ __forceinline__ float log2_fast(float x) { return __builtin_amdgcn_logf(x); }

#define LOG2E 1.4426950408889634f
#define LN2   0.6931471805599453f

// ---------------------------------------------------------------------------
// K1. Grid: 512 blocks x 256 threads (4 waves). Block = rows [bid*64, bid*64+64)
// = batch b = bid>>3, chunks c = (bid&7)*2 + {0,1}.
// Wave wv (0..3), q-group q (0..3): group grp = wv*4+q owns rows grp*4..grp*4+3.
// Lane p (0..15) covers cols {cc*128 + u*64 + p*4 | cc in 0..7, u in 0..1}.
// ---------------------------------------------------------------------------
__global__ __launch_bounds__(256, 4) void logits_chunk_kernel(
    const float* __restrict__ inp, const float* __restrict__ Wg,
    const float* __restrict__ bias, const float* __restrict__ trans,
    const int* __restrict__ mask, float* __restrict__ feats,
    float* __restrict__ P, float* __restrict__ out)
{
    if (blockIdx.x == 0 && threadIdx.x == 0) out[0] = 0.0f;  // for K3's atomics

    __shared__ float Wl[NLAB * HID];       // 36 KB
    __shared__ float femit[RPB][NLAB];     // 2.25 KB: this block's emissions
    const int tid = threadIdx.x;
    #pragma unroll
    for (int i = 0; i < 9; ++i)            // 2304 float4 over 256 threads
        ((float4*)Wl)[tid + i * 256] = ((const float4*)Wg)[tid + i * 256];
    __syncthreads();

    const int lane = tid & 63;
    const int wv   = tid >> 6;       // 0..3
    const int p    = lane & 15;      // column position within slice
    const int q    = lane >> 4;      // q-group within wave
    const int grp  = wv * 4 + q;     // 0..15
    const int lrow0 = grp * 4;       // local rows lrow0..lrow0+3
    const long grow0 = (long)blockIdx.x * RPB + lrow0;
    const float* rb = inp + grow0 * HID + p * 4;   // lane global base (row 0)
    const float* wb = Wl + p * 4;                  // lane LDS base

    float acc[4][NLAB];
    #pragma unroll
    for (int r = 0; r < 4; ++r)
        #pragma unroll
        for (int l = 0; l < NLAB; ++l) acc[r][l] = 0.0f;

    #pragma unroll 1
    for (int cc = 0; cc < 8; ++cc) {
        const int off = cc * 128;
        // 8 independent coalesced loads (16 p-lanes -> 256B contiguous each)
        float4 xs[4][2];
        #pragma unroll
        for (int r = 0; r < 4; ++r) {
            xs[r][0] = *(const float4*)(rb + r * HID + off);
            xs[r][1] = *(const float4*)(rb + r * HID + off + 64);
        }
        #pragma unroll
        for (int l = 0; l < NLAB; ++l) {
            const float* w = wb + l * HID + off;   // imm-offset ds_read_b128
            float4 w0 = *(const float4*)(w);
            float4 w1 = *(const float4*)(w + 64);
            #pragma unroll
            for (int r = 0; r < 4; ++r) {
                float a = acc[r][l];
                a = fmaf(xs[r][0].x, w0.x, a);
                a = fmaf(xs[r][0].y, w0.y, a);
                a = fmaf(xs[r][0].z, w0.z, a);
                a = fmaf(xs[r][0].w, w0.w, a);
                a = fmaf(xs[r][1].x, w1.x, a);
                a = fmaf(xs[r][1].y, w1.y, a);
                a = fmaf(xs[r][1].z, w1.z, a);
                a = fmaf(xs[r][1].w, w1.w, a);
                acc[r][l] = a;
            }
        }
    }

    // reduce across the 16-lane group (xor masks 1,2,4,8 stay in group)
    #pragma unroll
    for (int r = 0; r < 4; ++r) {
        #pragma unroll
        for (int l = 0; l < NLAB; ++l) {
            float a = acc[r][l];
            a += __shfl_xor(a, 8, 64);
            a += __shfl_xor(a, 4, 64);
            a += __shfl_xor(a, 2, 64);
            a += __shfl_xor(a, 1, 64);
            acc[r][l] = a;
        }
    }
    if (p == 0) {
        #pragma unroll
        for (int r = 0; r < 4; ++r) {
            float* o = feats + (grow0 + r) * NLAB;
            #pragma unroll
            for (int l = 0; l < NLAB; ++l) {
                float f = (acc[r][l] + bias[l]) * LOG2E;
                o[l] = f;  femit[lrow0 + r][l] = f;
            }
        }
    }
    __syncthreads();

    // ---- phase B: chunk recursions (4 waves cover the block's 2 chunks) ----
    const int half = wv >> 1;        // which of the block's 2 chunks
    const int sub  = wv & 1;         // 0: P-rows 0..6, 1: P-rows 7..8
    const int b = blockIdx.x >> 3;
    const int c = ((blockIdx.x & 7) << 1) | half;   // global chunk index
    const int crow0 = half * CHUNK;                 // femit row base

    int g = lane / 9;
    const int jj = lane - g * 9;     // 0..8 always
    bool act = sub ? (g < 2) : (g < 7);
    int i = act ? (sub * 7 + g) : 0; // P-row 0..8
    const int sbase = g * 9;

    float tr[NLAB];
    #pragma unroll
    for (int k = 0; k < NLAB; ++k) tr[k] = trans[k * NLAB + jj] * LOG2E;
    const float tri = trans[i * NLAB + jj] * LOG2E;

    const int* mb = mask + b * SEQ + c * CHUNK;   // chunk-local mask base
    const int ts = (c == 0) ? 1 : 0;              // chunk-local start step

    float a;
    {
        int m0 = mb[ts];
        float e0 = femit[crow0 + ts][jj];
        float aid = (i == jj) ? 0.0f : -1e30f;
        a = (m0 > 0) ? (tri + e0) : aid;
    }

    int m_nxt = mb[ts + 1];
    for (int t = ts + 1; t < CHUNK; ++t) {
        float e = femit[crow0 + t][jj];
        int  mt = m_nxt;
        if (t + 1 < CHUNK) m_nxt = mb[t + 1];     // prefetch next step's mask
        float v[NLAB];
        #pragma unroll
        for (int k = 0; k < NLAB; ++k) v[k] = __shfl(a, sbase + k, 64) + tr[k];
        float m01 = fmaxf(v[0], v[1]), m23 = fmaxf(v[2], v[3]);
        float m45 = fmaxf(v[4], v[5]), m67 = fmaxf(v[6], v[7]);
        float mx = fmaxf(fmaxf(fmaxf(m01, m23), fmaxf(m45, m67)), v[8]);
        float s = 0.0f;
        #pragma unroll
        for (int k = 0; k < NLAB; ++k) s += exp2_fast(v[k] - mx);
        float an = mx + log2_fast(s) + e;
        a = (mt > 0) ? an : a;
    }
    if (act)
        P[(long)(b * NCHUNK + c) * 81 + i * NLAB + jj] = a;
}

// ---------------------------------------------------------------------------
// K3: per-batch finalize. Grid: 64 blocks x 64.
//  - gold path score (all 64 lanes, strided over t, then wave-reduce)
//  - alpha = alpha0 ⊗ P_0 ⊗ ... ⊗ P_15 (lanes replicate j = lane%9)
//  - atomicAdd (norm - score) * ln2/B into out[0] (zeroed by K1)
// ---------------------------------------------------------------------------
__global__ __launch_bounds__(64) void final_kernel(
    const float* __restrict__ feats, const float* __restrict__ trans,
    const float* __restrict__ startv, const float* __restrict__ endv,
    const int* __restrict__ labels, const int* __restrict__ mask,
    const float* __restrict__ P, float* __restrict__ out)
{
    const int b = blockIdx.x, lane = threadIdx.x;
    const float* fb = feats + (long)b * SEQ * NLAB;
    const int* lb = labels + b * SEQ;
    const int* mb = mask + b * SEQ;

    // ---- gold score ----
    float gsum = 0.0f; int msum = 0;
    for (int t = lane; t < SEQ; t += 64) {
        int tag = lb[t];
        int mt = mb[t];
        if (mt > 0) {
            gsum += fb[t * NLAB + tag];            // feats already *K
            msum++;
            if (t > 0) gsum += trans[lb[t - 1] * NLAB + tag] * LOG2E;
        }
    }
    #pragma unroll
    for (int off = 32; off > 0; off >>= 1) {
        gsum += __shfl_xor(gsum, off, 64);
        msum += __shfl_xor(msum, off, 64);
    }

    // ---- alpha chain over chunk matrices ----
    const int j = lane % 9;      // lanes >=9 replicate; shuffles read lanes 0..8
    float al = fb[j] + startv[j] * LOG2E;
    const float* Pb = P + (long)b * NCHUNK * 81;
    float pc[NLAB];
    #pragma unroll
    for (int i = 0; i < NLAB; ++i) pc[i] = Pb[i * NLAB + j];
    #pragma unroll
    for (int c = 0; c < NCHUNK; ++c) {
        float pn[NLAB];
        if (c < NCHUNK - 1) {
            #pragma unroll
            for (int i = 0; i < NLAB; ++i) pn[i] = Pb[(c + 1) * 81 + i * NLAB + j];
        } else {
            #pragma unroll
            for (int i = 0; i < NLAB; ++i) pn[i] = 0.0f;
        }
        float v[NLAB];
        #pragma unroll
        for (int i = 0; i < NLAB; ++i) v[i] = __shfl(al, i, 64) + pc[i];
        float m01 = fmaxf(v[0], v[1]), m23 = fmaxf(v[2], v[3]);
        float m45 = fmaxf(v[4], v[5]), m67 = fmaxf(v[6], v[7]);
        float mx = fmaxf(fmaxf(fmaxf(m01, m23), fmaxf(m45, m67)), v[8]);
        float s = 0.0f;
        #pragma unroll
        for (int i = 0; i < NLAB; ++i) s += exp2_fast(v[i] - mx);
        al = mx + log2_fast(s);
        #pragma unroll
        for (int i = 0; i < NLAB; ++i) pc[i] = pn[i];
    }
    al += endv[j] * LOG2E;

    // LSE over j (lanes 0..8 hold the distinct values)
    float v[NLAB];
    #pragma unroll
    for (int i = 0; i < NLAB; ++i) v[i] = __shfl(al, i, 64);
    float m01 = fmaxf(v[0], v[1]), m23 = fmaxf(v[2], v[3]);
    float m45 = fmaxf(v[4], v[5]), m67 = fmaxf(v[6], v[7]);
    float mx = fmaxf(fmaxf(fmaxf(m01, m23), fmaxf(m45, m67)), v[8]);
    float s = 0.0f;
    #pragma unroll
    for (int i = 0; i < NLAB; ++i) s += exp2_fast(v[i] - mx);
    float norm = mx + log2_fast(s);

    if (lane == 0) {
        int li = (msum > 0) ? (msum - 1) : 0;
        float score = gsum + startv[lb[0]] * LOG2E + endv[lb[li]] * LOG2E;
        atomicAdd(out, (norm - score) * (LN2 / (float)BATCH));
    }
}

extern "C" void kernel_launch(void* const* d_in, const int* in_sizes, int n_in,
                              void* d_out, int out_size, void* d_ws, size_t ws_size,
                              hipStream_t stream)
{
    const float* inp    = (const float*)d_in[0];
    const int*   labels = (const int*)d_in[1];
    const int*   mask   = (const int*)d_in[2];
    const float* W      = (const float*)d_in[3];
    const float* bias   = (const float*)d_in[4];
    const float* trans  = (const float*)d_in[5];
    const float* startv = (const float*)d_in[6];
    const float* endv   = (const float*)d_in[7];

    float* feats = (float*)d_ws;                    // B*S*L = 294912 floats
    float* P     = feats + BATCH * SEQ * NLAB;      // B*NCHUNK*81 = 82944 floats
    float* out   = (float*)d_out;

    hipLaunchKernelGGL(logits_chunk_kernel, dim3(BATCH * SEQ / RPB), dim3(256), 0,
                       stream, inp, W, bias, trans, mask, feats, P, out);
    hipLaunchKernelGGL(final_kernel, dim3(BATCH), dim3(64), 0, stream,
                       feats, trans, startv, endv, labels, mask, P, out);
}

// Round 19
// 235.133 us; speedup vs baseline: 2.2155x; 1.0495x over previous
//
#include <hip/hip_runtime.h>

// CRF sequence labeling: B=64, S=512, H=1024, L=9
// Pipeline (2 kernels):
//   K1 logits_chunk_kernel (256 thr, 64 rows = 2 chunks per block, grid 512):
//        phase A (GEMM): feats[row][l] = (inp[row,:]·W[l,:] + b[l]) * log2e
//          R7: same layout as R6 (4 rows/lane, 8 independent coalesced float4
//          loads per 128-col slice, W via imm-offset broadcast ds_read_b128)
//          but NO second __launch_bounds__ arg. Measured evidence:
//            __launch_bounds__(256)    -> VGPR=100, no spill   (R3)
//            __launch_bounds__(512,4)  -> VGPR=64, 447MB spill (R5)
//            __launch_bounds__(256,4)  -> VGPR=64,  33MB spill (R6)
//          The waves-per-EU hint makes the backend target 8 waves/EU
//          (64 VGPR) even though LDS (39KB -> 4 blocks/CU) caps occupancy
//          at 4 waves/EU. Omit it; the default heuristic respects LDS.
//        phase B (waves 0-3): per chunk, 9 row-recursions of the 9x9
//          log2-semiring chunk transfer matrix P_c; 9-lane groups, shuffle
//          recursion; masked steps contribute identity.
//        Also zeroes out[0] for K3's atomic accumulation.
//   K3 final_kernel : per batch: gold path score + alpha0 ⊗ P_0 ⊗ ... ⊗ P_15;
//        atomicAdd((norm-score)*ln2/B) into out[0].
// All LSE math in base-2 domain (inputs pre-scaled by log2 e) so
// LSE = max + log2(sum 2^x) maps to raw v_exp_f32/v_log_f32.

#define BATCH 64
#define SEQ   512
#define HID   1024
#define NLAB  9
#define CHUNK 32
#define NCHUNK (SEQ / CHUNK)   // 16
#define RPB   64               // rows per block (= 2 chunks)

__device__ __forceinline__ float exp2_fast(float x) { return __builtin_amdgcn_exp2f(x); }
__device__ __forceinline__ float log2_fast(float x) { return __builtin_amdgcn_logf(x); }

#define LOG2E 1.4426950408889634f
#define LN2   0.6931471805599453f

// ---------------------------------------------------------------------------
// K1. Grid: 512 blocks x 256 threads (4 waves). Block = rows [bid*64, bid*64+64)
// = batch b = bid>>3, chunks c = (bid&7)*2 + {0,1}.
// Wave wv (0..3), q-group q (0..3): group grp = wv*4+q owns rows grp*4..grp*4+3.
// Lane p (0..15) covers cols {cc*128 + u*64 + p*4 | cc in 0..7, u in 0..1}.
// ---------------------------------------------------------------------------
__global__ __launch_bounds__(256) void logits_chunk_kernel(
    const float* __restrict__ inp, const float* __restrict__ Wg,
    const float* __restrict__ bias, const float* __restrict__ trans,
    const int* __restrict__ mask, float* __restrict__ feats,
    float* __restrict__ P, float* __restrict__ out)
{
    if (blockIdx.x == 0 && threadIdx.x == 0) out[0] = 0.0f;  // for K3's atomics

    __shared__ float Wl[NLAB * HID];       // 36 KB
    __shared__ float femit[RPB][NLAB];     // 2.25 KB: this block's emissions
    const int tid = threadIdx.x;
    #pragma unroll
    for (int i = 0; i < 9; ++i)            // 2304 float4 over 256 threads
        ((float4*)Wl)[tid + i * 256] = ((const float4*)Wg)[tid + i * 256];
    __syncthreads();

    const int lane = tid & 63;
    const int wv   = tid >> 6;       // 0..3
    const int p    = lane & 15;      // column position within slice
    const int q    = lane >> 4;      // q-group within wave
    const int grp  = wv * 4 + q;     // 0..15
    const int lrow0 = grp * 4;       // local rows lrow0..lrow0+3
    const long grow0 = (long)blockIdx.x * RPB + lrow0;
    const float* rb = inp + grow0 * HID + p * 4;   // lane global base (row 0)
    const float* wb = Wl + p * 4;                  // lane LDS base

    float acc[4][NLAB];
    #pragma unroll
    for (int r = 0; r < 4; ++r)
        #pragma unroll
        for (int l = 0; l < NLAB; ++l) acc[r][l] = 0.0f;

    #pragma unroll 1
    for (int cc = 0; cc < 8; ++cc) {
        const int off = cc * 128;
        // 8 independent coalesced loads (16 p-lanes -> 256B contiguous each)
        float4 xs[4][2];
        #pragma unroll
        for (int r = 0; r < 4; ++r) {
            xs[r][0] = *(const float4*)(rb + r * HID + off);
            xs[r][1] = *(const float4*)(rb + r * HID + off + 64);
        }
        #pragma unroll
        for (int l = 0; l < NLAB; ++l) {
            const float* w = wb + l * HID + off;   // imm-offset ds_read_b128
            float4 w0 = *(const float4*)(w);
            float4 w1 = *(const float4*)(w + 64);
            #pragma unroll
            for (int r = 0; r < 4; ++r) {
                float a = acc[r][l];
                a = fmaf(xs[r][0].x, w0.x, a);
                a = fmaf(xs[r][0].y, w0.y, a);
                a = fmaf(xs[r][0].z, w0.z, a);
                a = fmaf(xs[r][0].w, w0.w, a);
                a = fmaf(xs[r][1].x, w1.x, a);
                a = fmaf(xs[r][1].y, w1.y, a);
                a = fmaf(xs[r][1].z, w1.z, a);
                a = fmaf(xs[r][1].w, w1.w, a);
                acc[r][l] = a;
            }
        }
    }

    // reduce across the 16-lane group (xor masks 1,2,4,8 stay in group)
    #pragma unroll
    for (int r = 0; r < 4; ++r) {
        #pragma unroll
        for (int l = 0; l < NLAB; ++l) {
            float a = acc[r][l];
            a += __shfl_xor(a, 8, 64);
            a += __shfl_xor(a, 4, 64);
            a += __shfl_xor(a, 2, 64);
            a += __shfl_xor(a, 1, 64);
            acc[r][l] = a;
        }
    }
    if (p == 0) {
        #pragma unroll
        for (int r = 0; r < 4; ++r) {
            float* o = feats + (grow0 + r) * NLAB;
            #pragma unroll
            for (int l = 0; l < NLAB; ++l) {
                float f = (acc[r][l] + bias[l]) * LOG2E;
                o[l] = f;  femit[lrow0 + r][l] = f;
            }
        }
    }
    __syncthreads();

    // ---- phase B: chunk recursions (4 waves cover the block's 2 chunks) ----
    const int half = wv >> 1;        // which of the block's 2 chunks
    const int sub  = wv & 1;         // 0: P-rows 0..6, 1: P-rows 7..8
    const int b = blockIdx.x >> 3;
    const int c = ((blockIdx.x & 7) << 1) | half;   // global chunk index
    const int crow0 = half * CHUNK;                 // femit row base

    int g = lane / 9;
    const int jj = lane - g * 9;     // 0..8 always
    bool act = sub ? (g < 2) : (g < 7);
    int i = act ? (sub * 7 + g) : 0; // P-row 0..8
    const int sbase = g * 9;

    float tr[NLAB];
    #pragma unroll
    for (int k = 0; k < NLAB; ++k) tr[k] = trans[k * NLAB + jj] * LOG2E;
    const float tri = trans[i * NLAB + jj] * LOG2E;

    const int* mb = mask + b * SEQ + c * CHUNK;   // chunk-local mask base
    const int ts = (c == 0) ? 1 : 0;              // chunk-local start step

    float a;
    {
        int m0 = mb[ts];
        float e0 = femit[crow0 + ts][jj];
        float aid = (i == jj) ? 0.0f : -1e30f;
        a = (m0 > 0) ? (tri + e0) : aid;
    }

    int m_nxt = mb[ts + 1];
    for (int t = ts + 1; t < CHUNK; ++t) {
        float e = femit[crow0 + t][jj];
        int  mt = m_nxt;
        if (t + 1 < CHUNK) m_nxt = mb[t + 1];     // prefetch next step's mask
        float v[NLAB];
        #pragma unroll
        for (int k = 0; k < NLAB; ++k) v[k] = __shfl(a, sbase + k, 64) + tr[k];
        float m01 = fmaxf(v[0], v[1]), m23 = fmaxf(v[2], v[3]);
        float m45 = fmaxf(v[4], v[5]), m67 = fmaxf(v[6], v[7]);
        float mx = fmaxf(fmaxf(fmaxf(m01, m23), fmaxf(m45, m67)), v[8]);
        float s = 0.0f;
        #pragma unroll
        for (int k = 0; k < NLAB; ++k) s += exp2_fast(v[k] - mx);
        float an = mx + log2_fast(s) + e;
        a = (mt > 0) ? an : a;
    }
    if (act)
        P[(long)(b * NCHUNK + c) * 81 + i * NLAB + jj] = a;
}

// ---------------------------------------------------------------------------
// K3: per-batch finalize. Grid: 64 blocks x 64.
//  - gold path score (all 64 lanes, strided over t, then wave-reduce)
//  - alpha = alpha0 ⊗ P_0 ⊗ ... ⊗ P_15 (lanes replicate j = lane%9)
//  - atomicAdd (norm - score) * ln2/B into out[0] (zeroed by K1)
// ---------------------------------------------------------------------------
__global__ __launch_bounds__(64) void final_kernel(
    const float* __restrict__ feats, const float* __restrict__ trans,
    const float* __restrict__ startv, const float* __restrict__ endv,
    const int* __restrict__ labels, const int* __restrict__ mask,
    const float* __restrict__ P, float* __restrict__ out)
{
    const int b = blockIdx.x, lane = threadIdx.x;
    const float* fb = feats + (long)b * SEQ * NLAB;
    const int* lb = labels + b * SEQ;
    const int* mb = mask + b * SEQ;

    // ---- gold score ----
    float gsum = 0.0f; int msum = 0;
    for (int t = lane; t < SEQ; t += 64) {
        int tag = lb[t];
        int mt = mb[t];
        if (mt > 0) {
            gsum += fb[t * NLAB + tag];            // feats already *K
            msum++;
            if (t > 0) gsum += trans[lb[t - 1] * NLAB + tag] * LOG2E;
        }
    }
    #pragma unroll
    for (int off = 32; off > 0; off >>= 1) {
        gsum += __shfl_xor(gsum, off, 64);
        msum += __shfl_xor(msum, off, 64);
    }

    // ---- alpha chain over chunk matrices ----
    const int j = lane % 9;      // lanes >=9 replicate; shuffles read lanes 0..8
    float al = fb[j] + startv[j] * LOG2E;
    const float* Pb = P + (long)b * NCHUNK * 81;
    float pc[NLAB];
    #pragma unroll
    for (int i = 0; i < NLAB; ++i) pc[i] = Pb[i * NLAB + j];
    #pragma unroll
    for (int c = 0; c < NCHUNK; ++c) {
        float pn[NLAB];
        if (c < NCHUNK - 1) {
            #pragma unroll
            for (int i = 0; i < NLAB; ++i) pn[i] = Pb[(c + 1) * 81 + i * NLAB + j];
        } else {
            #pragma unroll
            for (int i = 0; i < NLAB; ++i) pn[i] = 0.0f;
        }
        float v[NLAB];
        #pragma unroll
        for (int i = 0; i < NLAB; ++i) v[i] = __shfl(al, i, 64) + pc[i];
        float m01 = fmaxf(v[0], v[1]), m23 = fmaxf(v[2], v[3]);
        float m45 = fmaxf(v[4], v[5]), m67 = fmaxf(v[6], v[7]);
        float mx = fmaxf(fmaxf(fmaxf(m01, m23), fmaxf(m45, m67)), v[8]);
        float s = 0.0f;
        #pragma unroll
        for (int i = 0; i < NLAB; ++i) s += exp2_fast(v[i] - mx);
        al = mx + log2_fast(s);
        #pragma unroll
        for (int i = 0; i < NLAB; ++i) pc[i] = pn[i];
    }
    al += endv[j] * LOG2E;

    // LSE over j (lanes 0..8 hold the distinct values)
    float v[NLAB];
    #pragma unroll
    for (int i = 0; i < NLAB; ++i) v[i] = __shfl(al, i, 64);
    float m01 = fmaxf(v[0], v[1]), m23 = fmaxf(v[2], v[3]);
    float m45 = fmaxf(v[4], v[5]), m67 = fmaxf(v[6], v[7]);
    float mx = fmaxf(fmaxf(fmaxf(m01, m23), fmaxf(m45, m67)), v[8]);
    float s = 0.0f;
    #pragma unroll
    for (int i = 0; i < NLAB; ++i) s += exp2_fast(v[i] - mx);
    float norm = mx + log2_fast(s);

    if (lane == 0) {
        int li = (msum > 0) ? (msum - 1) : 0;
        float score = gsum + startv[lb[0]] * LOG2E + endv[lb[li]] * LOG2E;
        atomicAdd(out, (norm - score) * (LN2 / (float)BATCH));
    }
}

extern "C" void kernel_launch(void* const* d_in, const int* in_sizes, int n_in,
                              void* d_out, int out_size, void* d_ws, size_t ws_size,
                              hipStream_t stream)
{
    const float* inp    = (const float*)d_in[0];
    const int*   labels = (const int*)d_in[1];
    const int*   mask   = (const int*)d_in[2];
    const float* W      = (const float*)d_in[3];
    const float* bias   = (const float*)d_in[4];
    const float* trans  = (const float*)d_in[5];
    const float* startv = (const float*)d_in[6];
    const float* endv   = (const float*)d_in[7];

    float* feats = (float*)d_ws;                    // B*S*L = 294912 floats
    float* P     = feats + BATCH * SEQ * NLAB;      // B*NCHUNK*81 = 82944 floats
    float* out   = (float*)d_out;

    hipLaunchKernelGGL(logits_chunk_kernel, dim3(BATCH * SEQ / RPB), dim3(256), 0,
                       stream, inp, W, bias, trans, mask, feats, P, out);
    hipLaunchKernelGGL(final_kernel, dim3(BATCH), dim3(64), 0, stream,
                       feats, trans, startv, endv, labels, mask, P, out);
}

// Round 21
// 232.638 us; speedup vs baseline: 2.2392x; 1.0107x over previous
//
#include <hip/hip_runtime.h>

// CRF sequence labeling: B=64, S=512, H=1024, L=9
// Pipeline (2 kernels):
//   K1 logits_chunk_kernel (256 thr, 32 rows = 1 chunk per block, grid 1024):
//        phase A (GEMM): feats[row][l] = (inp[row,:]·W[l,:] + b[l]) * log2e
//          R8: 2 rows/lane (16-lane group owns rows grp*2..+1), 8 slices of
//          128 cols, SOFTWARE-PIPELINED: xsA/xsB double buffer, next slice's
//          4 coalesced float4 loads issue before current slice's 144 FMAs.
//          1024 blocks -> 4 blocks/CU (38KB LDS) -> 16 waves/CU for latency
//          hiding (R7: 2 blocks/CU, occupancy counter showed only ~6 waves).
//          LAUNCH-BOUNDS LESSON (measured): single-arg __launch_bounds__(256)
//          -> VGPR=100 no spill; any second arg (waves/EU hint) -> VGPR=64 +
//          scratch spill (R5: 447MB, R6: 33MB). Never pass the second arg.
//        phase B (waves 0-1): 9 row-recursions of the 9x9 log2-semiring
//          chunk transfer matrix P_c; 9-lane groups, shuffle recursion;
//          masked steps contribute identity.
//        Also zeroes out[0] for K3's atomic accumulation.
//   K3 final_kernel : per batch: gold path score + alpha0 ⊗ P_0 ⊗ ... ⊗ P_15;
//        atomicAdd((norm-score)*ln2/B) into out[0].
// All LSE math in base-2 domain (inputs pre-scaled by log2 e) so
// LSE = max + log2(sum 2^x) maps to raw v_exp_f32/v_log_f32.
// Harness note: ~2x 512MB workspace re-poison fills (~77us each) dominate the
// measured total (~155us fixed); K1 is the only real lever.

#define BATCH 64
#define SEQ   512
#define HID   1024
#define NLAB  9
#define CHUNK 32
#define NCHUNK (SEQ / CHUNK)   // 16
#define RPB   32               // rows per block (= 1 chunk)

__device__ __forceinline__ float exp2_fast(float x) { return __builtin_amdgcn_exp2f(x); }
__device__ __forceinline__ float log2_fast(float x) { return __builtin_amdgcn_logf(x); }

#define LOG2E 1.4426950408889634f
#define LN2   0.6931471805599453f

// ---------------------------------------------------------------------------
// K1. Grid: 1024 blocks x 256 threads (4 waves). Block = chunk c = bid&15 of
// batch b = bid>>4 (rows [bid*32, bid*32+32)).
// GEMM: group grp = wv*4 + (lane>>4) owns rows grp*2, grp*2+1; lane p=lane&15
// covers cols {cc*128 + u*64 + p*4 | u in 0..1} per slice cc in 0..7.
// ---------------------------------------------------------------------------
#define LOADX(X, OFF)                                              \
    {   X[0][0] = *(const float4*)(rb + (OFF));                    \
        X[0][1] = *(const float4*)(rb + (OFF) + 64);               \
        X[1][0] = *(const float4*)(rb + HID + (OFF));              \
        X[1][1] = *(const float4*)(rb + HID + (OFF) + 64); }

#define FMAX(X, OFF)                                               \
    _Pragma("unroll")                                              \
    for (int l = 0; l < NLAB; ++l) {                               \
        const float* w = wb + l * HID + (OFF);                     \
        float4 w0 = *(const float4*)(w);                           \
        float4 w1 = *(const float4*)(w + 64);                      \
        _Pragma("unroll")                                          \
        for (int r = 0; r < 2; ++r) {                              \
            float a = acc[r][l];                                   \
            a = fmaf(X[r][0].x, w0.x, a);                          \
            a = fmaf(X[r][0].y, w0.y, a);                          \
            a = fmaf(X[r][0].z, w0.z, a);                          \
            a = fmaf(X[r][0].w, w0.w, a);                          \
            a = fmaf(X[r][1].x, w1.x, a);                          \
            a = fmaf(X[r][1].y, w1.y, a);                          \
            a = fmaf(X[r][1].z, w1.z, a);                          \
            a = fmaf(X[r][1].w, w1.w, a);                          \
            acc[r][l] = a;                                         \
        }                                                          \
    }

__global__ __launch_bounds__(256) void logits_chunk_kernel(
    const float* __restrict__ inp, const float* __restrict__ Wg,
    const float* __restrict__ bias, const float* __restrict__ trans,
    const int* __restrict__ mask, float* __restrict__ feats,
    float* __restrict__ P, float* __restrict__ out)
{
    if (blockIdx.x == 0 && threadIdx.x == 0) out[0] = 0.0f;  // for K3's atomics

    __shared__ float Wl[NLAB * HID];       // 36 KB
    __shared__ float femit[RPB][NLAB];     // 1.125 KB: this chunk's emissions
    const int tid = threadIdx.x;
    #pragma unroll
    for (int i = 0; i < 9; ++i)            // 2304 float4 over 256 threads
        ((float4*)Wl)[tid + i * 256] = ((const float4*)Wg)[tid + i * 256];
    __syncthreads();

    const int lane = tid & 63;
    const int wv   = tid >> 6;       // 0..3
    const int p    = lane & 15;      // column position within slice
    const int q    = lane >> 4;      // q-group within wave
    const int grp  = wv * 4 + q;     // 0..15
    const int lrow0 = grp * 2;       // local rows lrow0, lrow0+1
    const long grow0 = (long)blockIdx.x * RPB + lrow0;
    const float* rb = inp + grow0 * HID + p * 4;   // lane global base (row 0)
    const float* wb = Wl + p * 4;                  // lane LDS base

    float acc[2][NLAB];
    #pragma unroll
    for (int r = 0; r < 2; ++r)
        #pragma unroll
        for (int l = 0; l < NLAB; ++l) acc[r][l] = 0.0f;

    // software-pipelined over 8 slices (pairs): loads of next slice issue
    // before FMAs of current slice -> 4 loads always in flight per wave.
    float4 xsA[2][2], xsB[2][2];
    LOADX(xsA, 0);
    #pragma unroll 1
    for (int ccp = 0; ccp < 4; ++ccp) {
        const int offA = ccp * 256;          // even slice cols
        LOADX(xsB, offA + 128);              // prefetch odd slice
        FMAX(xsA, offA);
        if (ccp < 3) LOADX(xsA, offA + 256); // prefetch next even slice
        FMAX(xsB, offA + 128);
    }

    // reduce across the 16-lane group (xor masks 1,2,4,8 stay in group)
    #pragma unroll
    for (int r = 0; r < 2; ++r) {
        #pragma unroll
        for (int l = 0; l < NLAB; ++l) {
            float a = acc[r][l];
            a += __shfl_xor(a, 8, 64);
            a += __shfl_xor(a, 4, 64);
            a += __shfl_xor(a, 2, 64);
            a += __shfl_xor(a, 1, 64);
            acc[r][l] = a;
        }
    }
    if (p == 0) {
        #pragma unroll
        for (int r = 0; r < 2; ++r) {
            float* o = feats + (grow0 + r) * NLAB;
            #pragma unroll
            for (int l = 0; l < NLAB; ++l) {
                float f = (acc[r][l] + bias[l]) * LOG2E;
                o[l] = f;  femit[lrow0 + r][l] = f;
            }
        }
    }
    __syncthreads();

    // ---- phase B: chunk recursion (waves 0-1) ----
    if (wv >= 2) return;

    const int b = blockIdx.x >> 4;
    const int c = blockIdx.x & (NCHUNK - 1);

    int g = lane / 9;
    const int jj = lane - g * 9;     // 0..8 always
    bool act = (wv == 0) ? (g < 7) : (g < 2);
    int i = act ? (wv * 7 + g) : 0;  // P-row 0..8
    const int sbase = g * 9;

    float tr[NLAB];
    #pragma unroll
    for (int k = 0; k < NLAB; ++k) tr[k] = trans[k * NLAB + jj] * LOG2E;
    const float tri = trans[i * NLAB + jj] * LOG2E;

    const int* mb = mask + b * SEQ + c * CHUNK;   // chunk-local mask base
    const int ts = (c == 0) ? 1 : 0;              // chunk-local start step

    float a;
    {
        int m0 = mb[ts];
        float e0 = femit[ts][jj];
        float aid = (i == jj) ? 0.0f : -1e30f;
        a = (m0 > 0) ? (tri + e0) : aid;
    }

    int m_nxt = mb[ts + 1];
    for (int t = ts + 1; t < CHUNK; ++t) {
        float e = femit[t][jj];
        int  mt = m_nxt;
        if (t + 1 < CHUNK) m_nxt = mb[t + 1];     // prefetch next step's mask
        float v[NLAB];
        #pragma unroll
        for (int k = 0; k < NLAB; ++k) v[k] = __shfl(a, sbase + k, 64) + tr[k];
        float m01 = fmaxf(v[0], v[1]), m23 = fmaxf(v[2], v[3]);
        float m45 = fmaxf(v[4], v[5]), m67 = fmaxf(v[6], v[7]);
        float mx = fmaxf(fmaxf(fmaxf(m01, m23), fmaxf(m45, m67)), v[8]);
        float s = 0.0f;
        #pragma unroll
        for (int k = 0; k < NLAB; ++k) s += exp2_fast(v[k] - mx);
        float an = mx + log2_fast(s) + e;
        a = (mt > 0) ? an : a;
    }
    if (act)
        P[(long)(b * NCHUNK + c) * 81 + i * NLAB + jj] = a;
}

// ---------------------------------------------------------------------------
// K3: per-batch finalize. Grid: 64 blocks x 64.
//  - gold path score (all 64 lanes, strided over t, then wave-reduce)
//  - alpha = alpha0 ⊗ P_0 ⊗ ... ⊗ P_15 (lanes replicate j = lane%9)
//  - atomicAdd (norm - score) * ln2/B into out[0] (zeroed by K1)
// ---------------------------------------------------------------------------
__global__ __launch_bounds__(64) void final_kernel(
    const float* __restrict__ feats, const float* __restrict__ trans,
    const float* __restrict__ startv, const float* __restrict__ endv,
    const int* __restrict__ labels, const int* __restrict__ mask,
    const float* __restrict__ P, float* __restrict__ out)
{
    const int b = blockIdx.x, lane = threadIdx.x;
    const float* fb = feats + (long)b * SEQ * NLAB;
    const int* lb = labels + b * SEQ;
    const int* mb = mask + b * SEQ;

    // ---- gold score ----
    float gsum = 0.0f; int msum = 0;
    for (int t = lane; t < SEQ; t += 64) {
        int tag = lb[t];
        int mt = mb[t];
        if (mt > 0) {
            gsum += fb[t * NLAB + tag];            // feats already *K
            msum++;
            if (t > 0) gsum += trans[lb[t - 1] * NLAB + tag] * LOG2E;
        }
    }
    #pragma unroll
    for (int off = 32; off > 0; off >>= 1) {
        gsum += __shfl_xor(gsum, off, 64);
        msum += __shfl_xor(msum, off, 64);
    }

    // ---- alpha chain over chunk matrices ----
    const int j = lane % 9;      // lanes >=9 replicate; shuffles read lanes 0..8
    float al = fb[j] + startv[j] * LOG2E;
    const float* Pb = P + (long)b * NCHUNK * 81;
    float pc[NLAB];
    #pragma unroll
    for (int i = 0; i < NLAB; ++i) pc[i] = Pb[i * NLAB + j];
    #pragma unroll
    for (int c = 0; c < NCHUNK; ++c) {
        float pn[NLAB];
        if (c < NCHUNK - 1) {
            #pragma unroll
            for (int i = 0; i < NLAB; ++i) pn[i] = Pb[(c + 1) * 81 + i * NLAB + j];
        } else {
            #pragma unroll
            for (int i = 0; i < NLAB; ++i) pn[i] = 0.0f;
        }
        float v[NLAB];
        #pragma unroll
        for (int i = 0; i < NLAB; ++i) v[i] = __shfl(al, i, 64) + pc[i];
        float m01 = fmaxf(v[0], v[1]), m23 = fmaxf(v[2], v[3]);
        float m45 = fmaxf(v[4], v[5]), m67 = fmaxf(v[6], v[7]);
        float mx = fmaxf(fmaxf(fmaxf(m01, m23), fmaxf(m45, m67)), v[8]);
        float s = 0.0f;
        #pragma unroll
        for (int i = 0; i < NLAB; ++i) s += exp2_fast(v[i] - mx);
        al = mx + log2_fast(s);
        #pragma unroll
        for (int i = 0; i < NLAB; ++i) pc[i] = pn[i];
    }
    al += endv[j] * LOG2E;

    // LSE over j (lanes 0..8 hold the distinct values)
    float v[NLAB];
    #pragma unroll
    for (int i = 0; i < NLAB; ++i) v[i] = __shfl(al, i, 64);
    float m01 = fmaxf(v[0], v[1]), m23 = fmaxf(v[2], v[3]);
    float m45 = fmaxf(v[4], v[5]), m67 = fmaxf(v[6], v[7]);
    float mx = fmaxf(fmaxf(fmaxf(m01, m23), fmaxf(m45, m67)), v[8]);
    float s = 0.0f;
    #pragma unroll
    for (int i = 0; i < NLAB; ++i) s += exp2_fast(v[i] - mx);
    float norm = mx + log2_fast(s);

    if (lane == 0) {
        int li = (msum > 0) ? (msum - 1) : 0;
        float score = gsum + startv[lb[0]] * LOG2E + endv[lb[li]] * LOG2E;
        atomicAdd(out, (norm - score) * (LN2 / (float)BATCH));
    }
}

extern "C" void kernel_launch(void* const* d_in, const int* in_sizes, int n_in,
                              void* d_out, int out_size, void* d_ws, size_t ws_size,
                              hipStream_t stream)
{
    const float* inp    = (const float*)d_in[0];
    const int*   labels = (const int*)d_in[1];
    const int*   mask   = (const int*)d_in[2];
    const float* W      = (const float*)d_in[3];
    const float* bias   = (const float*)d_in[4];
    const float* trans  = (const float*)d_in[5];
    const float* startv = (const float*)d_in[6];
    const float* endv   = (const float*)d_in[7];

    float* feats = (float*)d_ws;                    // B*S*L = 294912 floats
    float* P     = feats + BATCH * SEQ * NLAB;      // B*NCHUNK*81 = 82944 floats
    float* out   = (float*)d_out;

    hipLaunchKernelGGL(logits_chunk_kernel, dim3(BATCH * SEQ / RPB), dim3(256), 0,
                       stream, inp, W, bias, trans, mask, feats, P, out);
    hipLaunchKernelGGL(final_kernel, dim3(BATCH), dim3(64), 0, stream,
                       feats, trans, startv, endv, labels, mask, P, out);
}